// Round 21
// baseline (127.670 us; speedup 1.0000x reference)
//
#include <hip/hip_runtime.h>

// MHA forward, round 21.
//  - attn_fm: V bypasses LDS entirely. K stays LDS-staged (dbuf); V fragments
//    load direct from L2-resident sigma-permuted Vp (4 heads pinned/XCD),
//    issued right after QK^T (~400cyc before PV). LDS/tile 80->40KB.
//  - gemm_qkv (reg-dbuf + Q pre-scaled by EXPC2), gemm_out, prep: r20 exact.
// B=2, S=2048, D=1024, H=16, DH=64.
//
// ws: xb 8@0 | Wt 8@8 | Qb 8@16 | Kb 8@24 | Vp 8@32 | Ab 8@40  (48MB)

#define AS1 __attribute__((address_space(1)))
#define AS3 __attribute__((address_space(3)))
#define EXPC2 0.04508422f  // (1/32) * log2(e), folded into Q at projection

typedef __attribute__((ext_vector_type(4))) float f32x4;
typedef __attribute__((ext_vector_type(8))) short bf16x8;

__device__ __forceinline__ void gload16(const void* g, void* l) {
  __builtin_amdgcn_global_load_lds((const AS1 unsigned int*)g,
                                   (AS3 unsigned int*)l, 16, 0, 0);
}
__device__ __forceinline__ unsigned short f2b(float f) {  // RNE fp32->bf16
  unsigned u = __float_as_uint(f);
  return (unsigned short)((u + 0x7FFFu + ((u >> 16) & 1u)) >> 16);
}
__device__ __forceinline__ float fexp2(float x) {
  float r;
  asm("v_exp_f32 %0, %1" : "=v"(r) : "v"(x));
  return r;
}
__device__ __forceinline__ unsigned cvtpk(float a, float b) {  // [a|b] bf16x2
  unsigned r;
  asm("v_cvt_pk_bf16_f32 %0, %1, %2" : "=v"(r) : "v"(a), "v"(b));
  return r;
}

// ---------------------------------------------------------------- prep ----
__global__ __launch_bounds__(256) void prep(
    const float* __restrict__ x, const float* __restrict__ W0,
    const float* __restrict__ W1, const float* __restrict__ W2,
    const float* __restrict__ W3, unsigned short* __restrict__ xb,
    unsigned short* __restrict__ Wt) {
  __shared__ float T[64][65];
  const int tid = threadIdx.x;
  const int bid = blockIdx.x;
  if (bid < 4096) {
    const size_t i = (size_t)(bid * 256 + tid) * 4;
    float4 v = *(const float4*)&x[i];
    uint2 o;
    o.x = f2b(v.x) | ((unsigned)f2b(v.y) << 16);
    o.y = f2b(v.z) | ((unsigned)f2b(v.w) << 16);
    *(uint2*)&xb[i] = o;
    return;
  }
  const int idx = bid - 4096;
  const int kb = (idx & 15) * 64, nb = ((idx >> 4) & 15) * 64, z = idx >> 8;
  const float* W = (z == 0) ? W0 : (z == 1) ? W1 : (z == 2) ? W2 : W3;
  unsigned short* D = Wt + (size_t)z * 1024 * 1024;
#pragma unroll
  for (int p = 0; p < 4; ++p) {
    const int s = p * 256 + tid;
    const int r = s >> 4, c4 = s & 15;
    float4 v = *(const float4*)&W[(size_t)(kb + r) * 1024 + nb + c4 * 4];
    T[r][c4 * 4 + 0] = v.x;
    T[r][c4 * 4 + 1] = v.y;
    T[r][c4 * 4 + 2] = v.z;
    T[r][c4 * 4 + 3] = v.w;
  }
  __syncthreads();
#pragma unroll
  for (int p = 0; p < 4; ++p) {
    const int s = p * 256 + tid;
    const int n = s >> 4, k4 = s & 15;
    uint2 o;
    o.x = f2b(T[k4 * 4 + 0][n]) | ((unsigned)f2b(T[k4 * 4 + 1][n]) << 16);
    o.y = f2b(T[k4 * 4 + 2][n]) | ((unsigned)f2b(T[k4 * 4 + 3][n]) << 16);
    *(uint2*)&D[(size_t)(nb + n) * 1024 + kb + k4 * 4] = o;
  }
}

// ------------------------------------------------------------ gemm_qkv ----
// r20 exact: 128^2 tile, 4 waves, BK=32, 4 LDS buffers + register fragment
// dbuf; Q epilogue pre-scales by EXPC2. Grid 768, XCD remap.
__global__ __launch_bounds__(256, 3) void gemm_qkv(
    const unsigned short* __restrict__ xb, const unsigned short* __restrict__ Wt,
    unsigned short* __restrict__ Qb, unsigned short* __restrict__ Kb,
    unsigned short* __restrict__ Vp) {
  __shared__ unsigned short smem[32768];

  const int tid = threadIdx.x, lane = tid & 63, w = tid >> 6;
  const int bid = blockIdx.x;
  const int xcd = bid & 7, pos = bid >> 3;
  const int sub = pos >> 5, idx = pos & 31;
  const int bm = xcd * 4 + (idx & 3);
  const int bn = sub * 8 + (idx >> 2);
  const int wr = w >> 1, wc = w & 1;

  f32x4 acc[4][4];
#pragma unroll
  for (int m = 0; m < 4; ++m)
#pragma unroll
    for (int n = 0; n < 4; ++n) acc[m][n] = (f32x4)0.0f;

  const int prow0 = tid >> 3, pc0 = tid & 7;
  const int u0 = pc0 ^ (prow0 & 7);
  const int rOff = 2 * prow0 + (u0 >> 2);
  const int cOff = (u0 & 3) * 8;

  const int fr = lane & 15, g = lane >> 4;
  const int frh = fr >> 1;
  const int pcx = ((((fr & 1) << 2) | g) ^ frh) * 8;

#define QST(BUF, KC)                                                          \
  {                                                                           \
    const size_t ko = (size_t)(KC) + cOff;                                    \
    gload16(&xb[(size_t)(bm * 128 + rOff) * 1024 + ko],                       \
            &smem[(BUF)*8192 + tid * 8]);                                     \
    gload16(&xb[(size_t)(bm * 128 + 64 + rOff) * 1024 + ko],                  \
            &smem[(BUF)*8192 + 2048 + tid * 8]);                              \
    gload16(&Wt[(size_t)(bn * 128 + rOff) * 1024 + ko],                       \
            &smem[(BUF)*8192 + 4096 + tid * 8]);                              \
    gload16(&Wt[(size_t)(bn * 128 + 64 + rOff) * 1024 + ko],                  \
            &smem[(BUF)*8192 + 6144 + tid * 8]);                              \
  }

#define RDF(CB, AF, BF)                                                       \
  {                                                                           \
    const unsigned short* Ab_ = &smem[(CB)*8192];                             \
    const unsigned short* Bb_ = &smem[(CB)*8192 + 4096];                      \
    _Pragma("unroll") for (int mf = 0; mf < 4; ++mf) AF[mf] =                 \
        *(const bf16x8*)&Ab_[(wr * 32 + mf * 8 + frh) * 64 + pcx];            \
    _Pragma("unroll") for (int nf = 0; nf < 4; ++nf) BF[nf] =                 \
        *(const bf16x8*)&Bb_[(wc * 32 + nf * 8 + frh) * 64 + pcx];            \
  }

#define MM(AF, BF)                                                           \
  {                                                                          \
    __builtin_amdgcn_s_setprio(1);                                           \
    _Pragma("unroll") for (int mf = 0; mf < 4; ++mf)                         \
        _Pragma("unroll") for (int nf = 0; nf < 4; ++nf) acc[mf][nf] =       \
            __builtin_amdgcn_mfma_f32_16x16x32_bf16(AF[mf], BF[nf],          \
                                                    acc[mf][nf], 0, 0, 0);   \
    __builtin_amdgcn_s_setprio(0);                                           \
  }

#define BODY(T, ACUR, BCUR, ANXT, BNXT)                                      \
  {                                                                          \
    if ((T) < 30) {                                                          \
      asm volatile("s_waitcnt vmcnt(4)" ::: "memory");                       \
    } else if ((T) == 30) {                                                  \
      asm volatile("s_waitcnt vmcnt(0)" ::: "memory");                       \
    }                                                                        \
    __builtin_amdgcn_sched_barrier(0);                                       \
    __builtin_amdgcn_s_barrier();                                            \
    __builtin_amdgcn_sched_barrier(0);                                       \
    if ((T) < 31) RDF(((T) + 1) & 3, ANXT, BNXT)                             \
    if ((T) < 29) QST(((T) + 3) & 3, ((T) + 3) * 32)                         \
    if ((T) < 31) {                                                          \
      asm volatile("s_waitcnt lgkmcnt(8)" ::: "memory");                     \
    } else {                                                                 \
      asm volatile("s_waitcnt lgkmcnt(0)" ::: "memory");                     \
    }                                                                        \
    __builtin_amdgcn_sched_barrier(0);                                       \
    MM(ACUR, BCUR)                                                           \
  }

  bf16x8 afA[4], bfA[4], afB[4], bfB[4];

  QST(0, 0)
  QST(1, 32)
  QST(2, 64)
  asm volatile("s_waitcnt vmcnt(8)" ::: "memory");
  __builtin_amdgcn_sched_barrier(0);
  __builtin_amdgcn_s_barrier();
  __builtin_amdgcn_sched_barrier(0);
  RDF(0, afA, bfA)

#pragma unroll 1
  for (int t2 = 0; t2 < 16; ++t2) {
    const int t = t2 * 2;
    BODY(t, afA, bfA, afB, bfB)
    BODY(t + 1, afB, bfB, afA, bfA)
  }

  if (bn < 16) {
    unsigned short* Ob = (bn < 8) ? Qb : Kb;
    const float qs = (bn < 8) ? EXPC2 : 1.0f;
    const int cbase = (bn & 7) * 128;
#pragma unroll
    for (int mf = 0; mf < 4; ++mf)
#pragma unroll
      for (int nf = 0; nf < 4; ++nf) {
        const int col = cbase + wc * 64 + nf * 16 + fr;
        const int h = col >> 6, d = col & 63;
#pragma unroll
        for (int rr = 0; rr < 4; ++rr) {
          const int m = bm * 128 + wr * 64 + mf * 16 + g * 4 + rr;
          const int b = m >> 11, s = m & 2047;
          Ob[((size_t)(b * 16 + h) * 2048 + s) * 64 + d] =
              f2b(acc[mf][nf][rr] * qs);
        }
      }
    return;
  }

  __syncthreads();
#pragma unroll
  for (int mf = 0; mf < 4; ++mf)
#pragma unroll
    for (int nf = 0; nf < 4; ++nf) {
      const int cl = wc * 64 + nf * 16 + fr;
#pragma unroll
      for (int rr = 0; rr < 4; ++rr) {
        const int ml = wr * 64 + mf * 16 + g * 4 + rr;
        const int u = ml & 63, a = u >> 4;
        const int sperm = (ml & 64) | ((a >> 1) * 32 + ((u >> 2) & 3) * 8 +
                                       (a & 1) * 4 + (u & 3));
        smem[cl * 132 + sperm] = f2b(acc[mf][nf][rr]);
      }
    }
  __syncthreads();
  const int l5 = lane & 31;
  const size_t sbase = (size_t)((bm * 128) & 2047);
  const int bV = bm >> 4;
#pragma unroll
  for (int it = 0; it < 16; ++it) {
    const int rl = w * 32 + it * 2 + (lane >> 5);
    const int rowg = (bn - 16) * 128 + rl;
    const int h = rowg >> 6, d = rowg & 63;
    uint2 v = *(const uint2*)&smem[rl * 132 + l5 * 4];
    *(uint2*)&Vp[((size_t)(bV * 16 + h) * 64 + d) * 2048 + sbase + l5 * 4] = v;
  }
#undef BODY
#undef MM
#undef RDF
#undef QST
}

// ------------------------------------------------------------ gemm_out ----
// Round-15 exact: counted-vmcnt, 128^2 tile, BK=64 (2 K-halves), 64KB LDS.
__global__ __launch_bounds__(256) void gemm_out(
    const unsigned short* __restrict__ A, const unsigned short* __restrict__ B,
    float* __restrict__ Of) {
  __shared__ unsigned short smem[32768];

  const int tid = threadIdx.x, lane = tid & 63, w = tid >> 6;
  const int bm = blockIdx.x >> 3, bn = blockIdx.x & 7;
  const int wr = w >> 1, wc = w & 1;

  f32x4 acc[4][4];
#pragma unroll
  for (int m = 0; m < 4; ++m)
#pragma unroll
    for (int n = 0; n < 4; ++n) acc[m][n] = (f32x4)0.0f;

  const int prow0 = tid >> 3, pc0 = tid & 7;
  const int u0 = pc0 ^ (prow0 & 7);
  const int rOff = 2 * prow0 + (u0 >> 2);
  const int cOff = (u0 & 3) * 8;

  const int fr = lane & 15, g = lane >> 4;
  const int frh = fr >> 1;
  const int pcx = ((((fr & 1) << 2) | g) ^ frh) * 8;

#define OSTAGE4(BUF, KS, KC)                                                  \
  {                                                                           \
    const size_t ko = (size_t)(KC) + (KS)*32 + cOff;                          \
    gload16(&A[(size_t)(bm * 128 + rOff) * 1024 + ko],                        \
            &smem[(BUF)*16384 + (KS)*4096 + tid * 8]);                        \
    gload16(&A[(size_t)(bm * 128 + 64 + rOff) * 1024 + ko],                   \
            &smem[(BUF)*16384 + (KS)*4096 + 2048 + tid * 8]);                 \
    gload16(&B[(size_t)(bn * 128 + rOff) * 1024 + ko],                        \
            &smem[(BUF)*16384 + 8192 + (KS)*4096 + tid * 8]);                 \
    gload16(&B[(size_t)(bn * 128 + 64 + rOff) * 1024 + ko],                   \
            &smem[(BUF)*16384 + 8192 + (KS)*4096 + 2048 + tid * 8]);          \
  }

#define OPHASE(CUR, KS, VMSTR, STAGESTMT)                                     \
  {                                                                           \
    asm volatile(VMSTR ::: "memory");                                         \
    __builtin_amdgcn_sched_barrier(0);                                        \
    __builtin_amdgcn_s_barrier();                                             \
    __builtin_amdgcn_sched_barrier(0);                                        \
    bf16x8 af[4], bf[4];                                                      \
    const unsigned short* Ab_ = &smem[(CUR)*16384 + (KS)*4096];               \
    const unsigned short* Bb_ = &smem[(CUR)*16384 + 8192 + (KS)*4096];        \
    _Pragma("unroll") for (int mf = 0; mf < 4; ++mf) af[mf] =                 \
        *(const bf16x8*)&Ab_[(wr * 32 + mf * 8 + frh) * 64 + pcx];            \
    _Pragma("unroll") for (int nf = 0; nf < 4; ++nf) bf[nf] =                 \
        *(const bf16x8*)&Bb_[(wc * 32 + nf * 8 + frh) * 64 + pcx];            \
    STAGESTMT;                                                                \
    __builtin_amdgcn_s_setprio(1);                                            \
    _Pragma("unroll") for (int mf = 0; mf < 4; ++mf)                          \
        _Pragma("unroll") for (int nf = 0; nf < 4; ++nf) acc[mf][nf] =        \
            __builtin_amdgcn_mfma_f32_16x16x32_bf16(af[mf], bf[nf],           \
                                                    acc[mf][nf], 0, 0, 0);    \
    __builtin_amdgcn_s_setprio(0);                                            \
  }

  OSTAGE4(0, 0, 0)
  OSTAGE4(0, 1, 0)

#pragma unroll 1
  for (int t = 0; t < 15; ++t) {
    const int cu_ = t & 1, nb_ = (t + 1) & 1;
    const int kc1 = (t + 1) * 64;
    OPHASE(cu_, 0, "s_waitcnt vmcnt(4)", OSTAGE4(nb_, 0, kc1))
    OPHASE(cu_, 1, "s_waitcnt vmcnt(4)", OSTAGE4(nb_, 1, kc1))
  }
  OPHASE(1, 0, "s_waitcnt vmcnt(4)", (void)0)
  OPHASE(1, 1, "s_waitcnt vmcnt(0)", (void)0)

#pragma unroll
  for (int mf = 0; mf < 4; ++mf)
#pragma unroll
    for (int nf = 0; nf < 4; ++nf) {
      const int col = bn * 128 + wc * 64 + nf * 16 + fr;
#pragma unroll
      for (int rr = 0; rr < 4; ++rr) {
        const int m = bm * 128 + wr * 64 + mf * 16 + g * 4 + rr;
        Of[(size_t)m * 1024 + col] = acc[mf][nf][rr];
      }
    }
#undef OPHASE
#undef OSTAGE4
}

// ----------------------------------------------------------- attention ----
// V-direct attention: K LDS-staged (dbuf, 16KB total), V fragments read
// straight from L2-resident sigma-permuted Vp (global), issued after QK^T.
// Fixed-reference softmax with scale pre-folded into Q: p = exp2(v).
// q-tile 64, kv-tile 64, grid 1024, 4 heads/XCD, balanced bq.
__global__ __launch_bounds__(256) void attn_fm(
    const unsigned short* __restrict__ Qb, const unsigned short* __restrict__ Kb,
    const unsigned short* __restrict__ Vp, unsigned short* __restrict__ Ab) {
  __shared__ unsigned short smem[8192];  // K dbuf 2x4096; Ot slab aliases

  const int tid = threadIdx.x, lane = tid & 63, w = tid >> 6;
  const int lo = lane & 15, hi = lane >> 4;

  const int id = blockIdx.x;
  const int bh = (id & 7) * 4 + ((id >> 3) & 3);
  const int rem = id >> 5;
  const int qtr = rem >> 3;
  const int g = rem & 7;
  const int bq = (qtr == 0)   ? 2 * g
                 : (qtr == 1) ? 2 * g + 1
                 : (qtr == 2) ? 31 - 2 * g
                              : 30 - 2 * g;
  const int qw = bq * 64 + w * 16;
  const size_t base = (size_t)bh * (2048 * 64);

  bf16x8 qf[2];
#pragma unroll
  for (int ks = 0; ks < 2; ++ks)
    qf[ks] =
        *(const bf16x8*)&Qb[base + (size_t)(qw + lo) * 64 + ks * 32 + hi * 8];

  f32x4 accO[4];
#pragma unroll
  for (int mf = 0; mf < 4; ++mf) accO[mf] = (f32x4)0.0f;
  float lpart = 0.0f;

  const int ntile = bq + 1;
  const unsigned short* kgb = Kb + base;
  const unsigned short* vgb = Vp + base;
  const int lseg = w * 512;

  // K-only staging (V bypasses LDS)
#define STAGE(BUF, KBASE)                                                    \
  {                                                                          \
    const int kb_ = (KBASE);                                                 \
    _Pragma("unroll") for (int qq = 0; qq < 2; ++qq) {                       \
      const int slot = qq * 256 + tid;                                       \
      const int row = slot >> 3, ch = (slot & 7) ^ (row & 7);                \
      gload16(kgb + (size_t)(kb_ + row) * 64 + ch * 8,                       \
              &smem[(BUF)*4096 + qq * 2048 + lseg]);                         \
    }                                                                        \
  }

  STAGE(0, 0)
  int cur = 0;

  for (int t = 0; t < ntile; ++t) {
    __syncthreads();
    if (t + 1 < ntile) STAGE(cur ^ 1, (t + 1) * 64)

    const int kb = t * 64;
    const int x7 = lo & 7;
    bf16x8 ka[2][4];
#pragma unroll
    for (int ks = 0; ks < 2; ++ks) {
      const int ch = (ks * 4 + hi) ^ x7;
#pragma unroll
      for (int kf = 0; kf < 4; ++kf)
        ka[ks][kf] =
            *(const bf16x8*)&smem[cur * 4096 + (kf * 16 + lo) * 64 + ch * 8];
    }
    f32x4 st[4];
#pragma unroll
    for (int kf = 0; kf < 4; ++kf) st[kf] = (f32x4)0.0f;
    __builtin_amdgcn_s_setprio(1);
#pragma unroll
    for (int ks = 0; ks < 2; ++ks)
#pragma unroll
      for (int kf = 0; kf < 4; ++kf)
        st[kf] = __builtin_amdgcn_mfma_f32_16x16x32_bf16(ka[ks][kf], qf[ks],
                                                         st[kf], 0, 0, 0);
    __builtin_amdgcn_s_setprio(0);

    // V fragments DIRECT from global (L2-resident; ~400cyc before PV use).
    // Derivation: LDS chunk (ks*4+hi)^x7 XOR staging swizzle ^(row&7)
    // cancels (row&7 == x7) -> linear global chunk ks*4+hi.
    bf16x8 va[2][4];
#pragma unroll
    for (int ks = 0; ks < 2; ++ks)
#pragma unroll
      for (int mf = 0; mf < 4; ++mf)
        va[ks][mf] = *(const bf16x8*)&vgb[(size_t)(mf * 16 + lo) * 2048 + kb +
                                          (ks * 4 + hi) * 8];

    float v[16];
#pragma unroll
    for (int kf = 0; kf < 4; ++kf)
#pragma unroll
      for (int rr = 0; rr < 4; ++rr) v[kf * 4 + rr] = st[kf][rr];
    if (kb + 63 > qw) {
      const int qg = qw + lo;
#pragma unroll
      for (int kf = 0; kf < 4; ++kf)
#pragma unroll
        for (int rr = 0; rr < 4; ++rr)
          if (kb + kf * 16 + hi * 4 + rr > qg) v[kf * 4 + rr] = -1e30f;
    }
    float p[16], rs = 0.0f;
#pragma unroll
    for (int i = 0; i < 16; ++i) {
      p[i] = fexp2(v[i]);  // scale pre-folded into Q; reference cancels
      rs += p[i];
    }
    lpart += rs;

    bf16x8 pb[2];
#pragma unroll
    for (int ks = 0; ks < 2; ++ks) {
      uint4 u;
      u.x = cvtpk(p[ks * 8 + 0], p[ks * 8 + 1]);
      u.y = cvtpk(p[ks * 8 + 2], p[ks * 8 + 3]);
      u.z = cvtpk(p[ks * 8 + 4], p[ks * 8 + 5]);
      u.w = cvtpk(p[ks * 8 + 6], p[ks * 8 + 7]);
      pb[ks] = *(bf16x8*)&u;
    }

    __builtin_amdgcn_s_setprio(1);
#pragma unroll
    for (int ks = 0; ks < 2; ++ks)
#pragma unroll
      for (int mf = 0; mf < 4; ++mf)
        accO[mf] = __builtin_amdgcn_mfma_f32_16x16x32_bf16(va[ks][mf], pb[ks],
                                                           accO[mf], 0, 0, 0);
    __builtin_amdgcn_s_setprio(0);
    cur ^= 1;
  }

  __syncthreads();  // K staging dead -> Ot slab may alias

  float l = lpart;
  l += __shfl_xor(l, 16);
  l += __shfl_xor(l, 32);
  const float linv = 1.0f / l;
  unsigned short* ot = &smem[w * 1152];
#pragma unroll
  for (int mf = 0; mf < 4; ++mf) {
    uint2 u;
    u.x = cvtpk(accO[mf][0] * linv, accO[mf][1] * linv);
    u.y = cvtpk(accO[mf][2] * linv, accO[mf][3] * linv);
    *(uint2*)&ot[lo * 72 + mf * 16 + hi * 4] = u;
  }
  const int b = bh >> 4, h = bh & 15;
  const int row = lane >> 2, cg = (lane & 3) * 16;
  uint4 o0 = *(const uint4*)&ot[row * 72 + cg];
  uint4 o1 = *(const uint4*)&ot[row * 72 + cg + 8];
  unsigned short* op = &Ab[(size_t)(b * 2048 + qw + row) * 1024 + h * 64 + cg];
  *(uint4*)op = o0;
  *(uint4*)(op + 8) = o1;
#undef STAGE
}

// -------------------------------------------------------------- launch ----
extern "C" void kernel_launch(void* const* d_in, const int* in_sizes, int n_in,
                              void* d_out, int out_size, void* d_ws,
                              size_t ws_size, hipStream_t stream) {
  (void)in_sizes; (void)n_in; (void)out_size; (void)ws_size;
  const float* x = (const float*)d_in[0];
  const float* Wq = (const float*)d_in[1];
  const float* Wk = (const float*)d_in[2];
  const float* Wv = (const float*)d_in[3];
  const float* Wo = (const float*)d_in[4];
  float* out = (float*)d_out;

  char* ws = (char*)d_ws;
  unsigned short* xb = (unsigned short*)(ws);                // 8MB
  unsigned short* Wt = (unsigned short*)(ws + (8u << 20));   // 4x2MB (q,k,v,o)
  unsigned short* Qb = (unsigned short*)(ws + (16u << 20));  // 8MB
  unsigned short* Kb = (unsigned short*)(ws + (24u << 20));  // 8MB
  unsigned short* Vp = (unsigned short*)(ws + (32u << 20));  // 8MB
  unsigned short* Ab = (unsigned short*)(ws + (40u << 20));  // 8MB
  unsigned short* Wto = Wt + (size_t)3 * 1024 * 1024;        // ELEMENT offset

  prep<<<dim3(5120), 256, 0, stream>>>(x, Wq, Wk, Wv, Wo, xb, Wt);
  gemm_qkv<<<dim3(768), 256, 0, stream>>>(xb, Wt, Qb, Kb, Vp);
  attn_fm<<<dim3(1024), 256, 0, stream>>>(Qb, Kb, Vp, Ab);
  gemm_out<<<dim3(256), 256, 0, stream>>>(Ab, Wto, out);
}

// Round 22
// 92.743 us; speedup vs baseline: 1.3766x; 1.3766x over previous
//
#include <hip/hip_runtime.h>

// MHA forward, round 22: revert to round-17 (best measured, 93.5us) plus the
// two r20-validated numeric trims: Q pre-scaled by EXPC2 in the GEMM epilogue,
// attn softmax p = exp2(v) directly (no fma/C24; global factor cancels).
// B=2, S=2048, D=1024, H=16, DH=64.
//
// ws: xb 8@0 | Wt 8@8 | Qb 8@16 | Kb 8@24 | Vp 8@32 | Ab 8@40  (48MB)

#define AS1 __attribute__((address_space(1)))
#define AS3 __attribute__((address_space(3)))
#define EXPC2 0.04508422f  // (1/32) * log2(e), folded into Q at projection

typedef __attribute__((ext_vector_type(4))) float f32x4;
typedef __attribute__((ext_vector_type(8))) short bf16x8;

__device__ __forceinline__ void gload16(const void* g, void* l) {
  __builtin_amdgcn_global_load_lds((const AS1 unsigned int*)g,
                                   (AS3 unsigned int*)l, 16, 0, 0);
}
__device__ __forceinline__ unsigned short f2b(float f) {  // RNE fp32->bf16
  unsigned u = __float_as_uint(f);
  return (unsigned short)((u + 0x7FFFu + ((u >> 16) & 1u)) >> 16);
}
__device__ __forceinline__ float fexp2(float x) {
  float r;
  asm("v_exp_f32 %0, %1" : "=v"(r) : "v"(x));
  return r;
}
__device__ __forceinline__ unsigned cvtpk(float a, float b) {  // [a|b] bf16x2
  unsigned r;
  asm("v_cvt_pk_bf16_f32 %0, %1, %2" : "=v"(r) : "v"(a), "v"(b));
  return r;
}

// ---------------------------------------------------------------- prep ----
__global__ __launch_bounds__(256) void prep(
    const float* __restrict__ x, const float* __restrict__ W0,
    const float* __restrict__ W1, const float* __restrict__ W2,
    const float* __restrict__ W3, unsigned short* __restrict__ xb,
    unsigned short* __restrict__ Wt) {
  __shared__ float T[64][65];
  const int tid = threadIdx.x;
  const int bid = blockIdx.x;
  if (bid < 4096) {
    const size_t i = (size_t)(bid * 256 + tid) * 4;
    float4 v = *(const float4*)&x[i];
    uint2 o;
    o.x = f2b(v.x) | ((unsigned)f2b(v.y) << 16);
    o.y = f2b(v.z) | ((unsigned)f2b(v.w) << 16);
    *(uint2*)&xb[i] = o;
    return;
  }
  const int idx = bid - 4096;
  const int kb = (idx & 15) * 64, nb = ((idx >> 4) & 15) * 64, z = idx >> 8;
  const float* W = (z == 0) ? W0 : (z == 1) ? W1 : (z == 2) ? W2 : W3;
  unsigned short* D = Wt + (size_t)z * 1024 * 1024;
#pragma unroll
  for (int p = 0; p < 4; ++p) {
    const int s = p * 256 + tid;
    const int r = s >> 4, c4 = s & 15;
    float4 v = *(const float4*)&W[(size_t)(kb + r) * 1024 + nb + c4 * 4];
    T[r][c4 * 4 + 0] = v.x;
    T[r][c4 * 4 + 1] = v.y;
    T[r][c4 * 4 + 2] = v.z;
    T[r][c4 * 4 + 3] = v.w;
  }
  __syncthreads();
#pragma unroll
  for (int p = 0; p < 4; ++p) {
    const int s = p * 256 + tid;
    const int n = s >> 4, k4 = s & 15;
    uint2 o;
    o.x = f2b(T[k4 * 4 + 0][n]) | ((unsigned)f2b(T[k4 * 4 + 1][n]) << 16);
    o.y = f2b(T[k4 * 4 + 2][n]) | ((unsigned)f2b(T[k4 * 4 + 3][n]) << 16);
    *(uint2*)&D[(size_t)(nb + n) * 1024 + kb + k4 * 4] = o;
  }
}

// ------------------------------------------------------------ gemm_qkv ----
// Round-17 exact: 128^2 tile, 4 waves, BK=64 (2 K-halves), counted-vmcnt
// phases, 64KB LDS, grid 768 linear (bm=id/24, bn=id%24).
// Q epilogue pre-scales by EXPC2 (r20-validated).
__global__ __launch_bounds__(256) void gemm_qkv(
    const unsigned short* __restrict__ xb, const unsigned short* __restrict__ Wt,
    unsigned short* __restrict__ Qb, unsigned short* __restrict__ Kb,
    unsigned short* __restrict__ Vp) {
  __shared__ unsigned short smem[32768];  // 64KB; V slab [128][132] aliases

  const int tid = threadIdx.x, lane = tid & 63, w = tid >> 6;
  const int bm = blockIdx.x / 24, bn = blockIdx.x % 24;
  const int wr = w >> 1, wc = w & 1;

  f32x4 acc[4][4];
#pragma unroll
  for (int m = 0; m < 4; ++m)
#pragma unroll
    for (int n = 0; n < 4; ++n) acc[m][n] = (f32x4)0.0f;

  const int prow0 = tid >> 3, pc0 = tid & 7;
  const int u0 = pc0 ^ (prow0 & 7);
  const int rOff = 2 * prow0 + (u0 >> 2);
  const int cOff = (u0 & 3) * 8;

  const int fr = lane & 15, g = lane >> 4;
  const int frh = fr >> 1;
  const int pcx = ((((fr & 1) << 2) | g) ^ frh) * 8;

#define QSTAGE4(BUF, KS, KC)                                                  \
  {                                                                           \
    const size_t ko = (size_t)(KC) + (KS)*32 + cOff;                          \
    gload16(&xb[(size_t)(bm * 128 + rOff) * 1024 + ko],                       \
            &smem[(BUF)*16384 + (KS)*4096 + tid * 8]);                        \
    gload16(&xb[(size_t)(bm * 128 + 64 + rOff) * 1024 + ko],                  \
            &smem[(BUF)*16384 + (KS)*4096 + 2048 + tid * 8]);                 \
    gload16(&Wt[(size_t)(bn * 128 + rOff) * 1024 + ko],                       \
            &smem[(BUF)*16384 + 8192 + (KS)*4096 + tid * 8]);                 \
    gload16(&Wt[(size_t)(bn * 128 + 64 + rOff) * 1024 + ko],                  \
            &smem[(BUF)*16384 + 8192 + (KS)*4096 + 2048 + tid * 8]);          \
  }

#define QPHASE(CUR, KS, VMSTR, STAGESTMT)                                     \
  {                                                                           \
    asm volatile(VMSTR ::: "memory");                                         \
    __builtin_amdgcn_sched_barrier(0);                                        \
    __builtin_amdgcn_s_barrier();                                             \
    __builtin_amdgcn_sched_barrier(0);                                        \
    bf16x8 af[4], bf[4];                                                      \
    const unsigned short* Ab_ = &smem[(CUR)*16384 + (KS)*4096];               \
    const unsigned short* Bb_ = &smem[(CUR)*16384 + 8192 + (KS)*4096];        \
    _Pragma("unroll") for (int mf = 0; mf < 4; ++mf) af[mf] =                 \
        *(const bf16x8*)&Ab_[(wr * 32 + mf * 8 + frh) * 64 + pcx];            \
    _Pragma("unroll") for (int nf = 0; nf < 4; ++nf) bf[nf] =                 \
        *(const bf16x8*)&Bb_[(wc * 32 + nf * 8 + frh) * 64 + pcx];            \
    STAGESTMT;                                                                \
    __builtin_amdgcn_s_setprio(1);                                            \
    _Pragma("unroll") for (int mf = 0; mf < 4; ++mf)                          \
        _Pragma("unroll") for (int nf = 0; nf < 4; ++nf) acc[mf][nf] =        \
            __builtin_amdgcn_mfma_f32_16x16x32_bf16(af[mf], bf[nf],           \
                                                    acc[mf][nf], 0, 0, 0);    \
    __builtin_amdgcn_s_setprio(0);                                            \
  }

  QSTAGE4(0, 0, 0)
  QSTAGE4(0, 1, 0)

#pragma unroll 1
  for (int t = 0; t < 15; ++t) {
    const int cu_ = t & 1, nb_ = (t + 1) & 1;
    const int kc1 = (t + 1) * 64;
    QPHASE(cu_, 0, "s_waitcnt vmcnt(4)", QSTAGE4(nb_, 0, kc1))
    QPHASE(cu_, 1, "s_waitcnt vmcnt(4)", QSTAGE4(nb_, 1, kc1))
  }
  QPHASE(1, 0, "s_waitcnt vmcnt(4)", (void)0)
  QPHASE(1, 1, "s_waitcnt vmcnt(0)", (void)0)

  // ------------------------------- epilogues -------------------------------
  if (bn < 16) {
    unsigned short* Ob = (bn < 8) ? Qb : Kb;
    const float qs = (bn < 8) ? EXPC2 : 1.0f;  // fold softmax scale into Q
    const int cbase = (bn & 7) * 128;
#pragma unroll
    for (int mf = 0; mf < 4; ++mf)
#pragma unroll
      for (int nf = 0; nf < 4; ++nf) {
        const int col = cbase + wc * 64 + nf * 16 + fr;
        const int h = col >> 6, d = col & 63;
#pragma unroll
        for (int rr = 0; rr < 4; ++rr) {
          const int m = bm * 128 + wr * 64 + mf * 16 + g * 4 + rr;
          const int b = m >> 11, s = m & 2047;
          Ob[((size_t)(b * 16 + h) * 2048 + s) * 64 + d] =
              f2b(acc[mf][nf][rr] * qs);
        }
      }
    return;
  }

  // V epilogue: LDS-transpose slab [cl 128][sperm 132] (round-9 validated)
  __syncthreads();
#pragma unroll
  for (int mf = 0; mf < 4; ++mf)
#pragma unroll
    for (int nf = 0; nf < 4; ++nf) {
      const int cl = wc * 64 + nf * 16 + fr;
#pragma unroll
      for (int rr = 0; rr < 4; ++rr) {
        const int ml = wr * 64 + mf * 16 + g * 4 + rr;
        const int u = ml & 63, a = u >> 4;
        const int sperm = (ml & 64) | ((a >> 1) * 32 + ((u >> 2) & 3) * 8 +
                                       (a & 1) * 4 + (u & 3));
        smem[cl * 132 + sperm] = f2b(acc[mf][nf][rr]);
      }
    }
  __syncthreads();
  const int l5 = lane & 31;
  const size_t sbase = (size_t)((bm * 128) & 2047);
  const int bV = bm >> 4;
#pragma unroll
  for (int it = 0; it < 16; ++it) {
    const int rl = w * 32 + it * 2 + (lane >> 5);
    const int rowg = (bn - 16) * 128 + rl;
    const int h = rowg >> 6, d = rowg & 63;
    uint2 v = *(const uint2*)&smem[rl * 132 + l5 * 4];
    *(uint2*)&Vp[((size_t)(bV * 16 + h) * 64 + d) * 2048 + sbase + l5 * 4] = v;
  }
#undef QPHASE
#undef QSTAGE4
}

// ------------------------------------------------------------ gemm_out ----
// Round-15 exact: counted-vmcnt, 128^2 tile, BK=64 (2 K-halves), 64KB LDS.
__global__ __launch_bounds__(256) void gemm_out(
    const unsigned short* __restrict__ A, const unsigned short* __restrict__ B,
    float* __restrict__ Of) {
  __shared__ unsigned short smem[32768];

  const int tid = threadIdx.x, lane = tid & 63, w = tid >> 6;
  const int bm = blockIdx.x >> 3, bn = blockIdx.x & 7;
  const int wr = w >> 1, wc = w & 1;

  f32x4 acc[4][4];
#pragma unroll
  for (int m = 0; m < 4; ++m)
#pragma unroll
    for (int n = 0; n < 4; ++n) acc[m][n] = (f32x4)0.0f;

  const int prow0 = tid >> 3, pc0 = tid & 7;
  const int u0 = pc0 ^ (prow0 & 7);
  const int rOff = 2 * prow0 + (u0 >> 2);
  const int cOff = (u0 & 3) * 8;

  const int fr = lane & 15, g = lane >> 4;
  const int frh = fr >> 1;
  const int pcx = ((((fr & 1) << 2) | g) ^ frh) * 8;

#define OSTAGE4(BUF, KS, KC)                                                  \
  {                                                                           \
    const size_t ko = (size_t)(KC) + (KS)*32 + cOff;                          \
    gload16(&A[(size_t)(bm * 128 + rOff) * 1024 + ko],                        \
            &smem[(BUF)*16384 + (KS)*4096 + tid * 8]);                        \
    gload16(&A[(size_t)(bm * 128 + 64 + rOff) * 1024 + ko],                   \
            &smem[(BUF)*16384 + (KS)*4096 + 2048 + tid * 8]);                 \
    gload16(&B[(size_t)(bn * 128 + rOff) * 1024 + ko],                        \
            &smem[(BUF)*16384 + 8192 + (KS)*4096 + tid * 8]);                 \
    gload16(&B[(size_t)(bn * 128 + 64 + rOff) * 1024 + ko],                   \
            &smem[(BUF)*16384 + 8192 + (KS)*4096 + 2048 + tid * 8]);          \
  }

#define OPHASE(CUR, KS, VMSTR, STAGESTMT)                                     \
  {                                                                           \
    asm volatile(VMSTR ::: "memory");                                         \
    __builtin_amdgcn_sched_barrier(0);                                        \
    __builtin_amdgcn_s_barrier();                                             \
    __builtin_amdgcn_sched_barrier(0);                                        \
    bf16x8 af[4], bf[4];                                                      \
    const unsigned short* Ab_ = &smem[(CUR)*16384 + (KS)*4096];               \
    const unsigned short* Bb_ = &smem[(CUR)*16384 + 8192 + (KS)*4096];        \
    _Pragma("unroll") for (int mf = 0; mf < 4; ++mf) af[mf] =                 \
        *(const bf16x8*)&Ab_[(wr * 32 + mf * 8 + frh) * 64 + pcx];            \
    _Pragma("unroll") for (int nf = 0; nf < 4; ++nf) bf[nf] =                 \
        *(const bf16x8*)&Bb_[(wc * 32 + nf * 8 + frh) * 64 + pcx];            \
    STAGESTMT;                                                                \
    __builtin_amdgcn_s_setprio(1);                                            \
    _Pragma("unroll") for (int mf = 0; mf < 4; ++mf)                          \
        _Pragma("unroll") for (int nf = 0; nf < 4; ++nf) acc[mf][nf] =        \
            __builtin_amdgcn_mfma_f32_16x16x32_bf16(af[mf], bf[nf],           \
                                                    acc[mf][nf], 0, 0, 0);    \
    __builtin_amdgcn_s_setprio(0);                                            \
  }

  OSTAGE4(0, 0, 0)
  OSTAGE4(0, 1, 0)

#pragma unroll 1
  for (int t = 0; t < 15; ++t) {
    const int cu_ = t & 1, nb_ = (t + 1) & 1;
    const int kc1 = (t + 1) * 64;
    OPHASE(cu_, 0, "s_waitcnt vmcnt(4)", OSTAGE4(nb_, 0, kc1))
    OPHASE(cu_, 1, "s_waitcnt vmcnt(4)", OSTAGE4(nb_, 1, kc1))
  }
  OPHASE(1, 0, "s_waitcnt vmcnt(4)", (void)0)
  OPHASE(1, 1, "s_waitcnt vmcnt(0)", (void)0)

#pragma unroll
  for (int mf = 0; mf < 4; ++mf)
#pragma unroll
    for (int nf = 0; nf < 4; ++nf) {
      const int col = bn * 128 + wc * 64 + nf * 16 + fr;
#pragma unroll
      for (int rr = 0; rr < 4; ++rr) {
        const int m = bm * 128 + wr * 64 + mf * 16 + g * 4 + rr;
        Of[(size_t)m * 1024 + col] = acc[mf][nf][rr];
      }
    }
#undef OPHASE
#undef OSTAGE4
}

// ----------------------------------------------------------- attention ----
// Round-17 structure (LDS-staged K AND V, dbuf, 32KB), with p = exp2(v)
// (scale pre-folded into Q). q-tile 64, kv-tile 64, grid 1024 balanced.
__global__ __launch_bounds__(256) void attn_fm(
    const unsigned short* __restrict__ Qb, const unsigned short* __restrict__ Kb,
    const unsigned short* __restrict__ Vp, unsigned short* __restrict__ Ab) {
  __shared__ unsigned short smem[16384];

  const int tid = threadIdx.x, lane = tid & 63, w = tid >> 6;
  const int lo = lane & 15, hi = lane >> 4;

  const int id = blockIdx.x;
  const int qtr = id >> 8;      // 0..3
  const int g = (id >> 5) & 7;  // 0..7
  const int bh = id & 31;
  const int bq = (qtr == 0)   ? 2 * g
                 : (qtr == 1) ? 2 * g + 1
                 : (qtr == 2) ? 31 - 2 * g
                              : 30 - 2 * g;
  const int qw = bq * 64 + w * 16;
  const size_t base = (size_t)bh * (2048 * 64);

  bf16x8 qf[2];
#pragma unroll
  for (int ks = 0; ks < 2; ++ks)
    qf[ks] =
        *(const bf16x8*)&Qb[base + (size_t)(qw + lo) * 64 + ks * 32 + hi * 8];

  f32x4 accO[4];
#pragma unroll
  for (int mf = 0; mf < 4; ++mf) accO[mf] = (f32x4)0.0f;
  float lpart = 0.0f;

  const int ntile = bq + 1;
  const unsigned short* kgb = Kb + base;
  const unsigned short* vgb = Vp + base;
  const int lseg = w * 512;

#define STAGE(BUF, KBASE)                                                    \
  {                                                                          \
    const int kb_ = (KBASE);                                                 \
    _Pragma("unroll") for (int qq = 0; qq < 2; ++qq) {                       \
      const int slot = qq * 256 + tid;                                       \
      const int row = slot >> 3, ch = (slot & 7) ^ (row & 7);                \
      gload16(kgb + (size_t)(kb_ + row) * 64 + ch * 8,                       \
              &smem[(BUF)*4096 + qq * 2048 + lseg]);                         \
      gload16(vgb + (size_t)row * 2048 + kb_ + ch * 8,                       \
              &smem[8192 + (BUF)*4096 + qq * 2048 + lseg]);                  \
    }                                                                        \
  }

  STAGE(0, 0)
  int cur = 0;

  for (int t = 0; t < ntile; ++t) {
    __syncthreads();
    if (t + 1 < ntile) STAGE(cur ^ 1, (t + 1) * 64)

    const int kb = t * 64;
    const int x7 = lo & 7;
    bf16x8 ka[2][4];
#pragma unroll
    for (int ks = 0; ks < 2; ++ks) {
      const int ch = (ks * 4 + hi) ^ x7;
#pragma unroll
      for (int kf = 0; kf < 4; ++kf)
        ka[ks][kf] =
            *(const bf16x8*)&smem[cur * 4096 + (kf * 16 + lo) * 64 + ch * 8];
    }
    f32x4 st[4];
#pragma unroll
    for (int kf = 0; kf < 4; ++kf) st[kf] = (f32x4)0.0f;
    __builtin_amdgcn_s_setprio(1);
#pragma unroll
    for (int ks = 0; ks < 2; ++ks)
#pragma unroll
      for (int kf = 0; kf < 4; ++kf)
        st[kf] = __builtin_amdgcn_mfma_f32_16x16x32_bf16(ka[ks][kf], qf[ks],
                                                         st[kf], 0, 0, 0);
    __builtin_amdgcn_s_setprio(0);

    bf16x8 va[2][4];
#pragma unroll
    for (int ks = 0; ks < 2; ++ks) {
      const int ch = (ks * 4 + hi) ^ x7;
#pragma unroll
      for (int mf = 0; mf < 4; ++mf)
        va[ks][mf] = *(const bf16x8*)&smem[8192 + cur * 4096 +
                                           (mf * 16 + lo) * 64 + ch * 8];
    }

    float v[16];
#pragma unroll
    for (int kf = 0; kf < 4; ++kf)
#pragma unroll
      for (int rr = 0; rr < 4; ++rr) v[kf * 4 + rr] = st[kf][rr];
    if (kb + 63 > qw) {
      const int qg = qw + lo;
#pragma unroll
      for (int kf = 0; kf < 4; ++kf)
#pragma unroll
        for (int rr = 0; rr < 4; ++rr)
          if (kb + kf * 16 + hi * 4 + rr > qg) v[kf * 4 + rr] = -1e30f;
    }
    float p[16], rs = 0.0f;
#pragma unroll
    for (int i = 0; i < 16; ++i) {
      p[i] = fexp2(v[i]);  // scale pre-folded into Q; reference cancels
      rs += p[i];
    }
    lpart += rs;

    bf16x8 pb[2];
#pragma unroll
    for (int ks = 0; ks < 2; ++ks) {
      uint4 u;
      u.x = cvtpk(p[ks * 8 + 0], p[ks * 8 + 1]);
      u.y = cvtpk(p[ks * 8 + 2], p[ks * 8 + 3]);
      u.z = cvtpk(p[ks * 8 + 4], p[ks * 8 + 5]);
      u.w = cvtpk(p[ks * 8 + 6], p[ks * 8 + 7]);
      pb[ks] = *(bf16x8*)&u;
    }

    __builtin_amdgcn_s_setprio(1);
#pragma unroll
    for (int ks = 0; ks < 2; ++ks)
#pragma unroll
      for (int mf = 0; mf < 4; ++mf)
        accO[mf] = __builtin_amdgcn_mfma_f32_16x16x32_bf16(va[ks][mf], pb[ks],
                                                           accO[mf], 0, 0, 0);
    __builtin_amdgcn_s_setprio(0);
    cur ^= 1;
  }

  __syncthreads();

  float l = lpart;
  l += __shfl_xor(l, 16);
  l += __shfl_xor(l, 32);
  const float linv = 1.0f / l;
  unsigned short* ot = &smem[w * 1152];
#pragma unroll
  for (int mf = 0; mf < 4; ++mf) {
    uint2 u;
    u.x = cvtpk(accO[mf][0] * linv, accO[mf][1] * linv);
    u.y = cvtpk(accO[mf][2] * linv, accO[mf][3] * linv);
    *(uint2*)&ot[lo * 72 + mf * 16 + hi * 4] = u;
  }
  const int b = bh >> 4, h = bh & 15;
  const int row = lane >> 2, cg = (lane & 3) * 16;
  uint4 o0 = *(const uint4*)&ot[row * 72 + cg];
  uint4 o1 = *(const uint4*)&ot[row * 72 + cg + 8];
  unsigned short* op = &Ab[(size_t)(b * 2048 + qw + row) * 1024 + h * 64 + cg];
  *(uint4*)op = o0;
  *(uint4*)(op + 8) = o1;
#undef STAGE
}

// -------------------------------------------------------------- launch ----
extern "C" void kernel_launch(void* const* d_in, const int* in_sizes, int n_in,
                              void* d_out, int out_size, void* d_ws,
                              size_t ws_size, hipStream_t stream) {
  (void)in_sizes; (void)n_in; (void)out_size; (void)ws_size;
  const float* x = (const float*)d_in[0];
  const float* Wq = (const float*)d_in[1];
  const float* Wk = (const float*)d_in[2];
  const float* Wv = (const float*)d_in[3];
  const float* Wo = (const float*)d_in[4];
  float* out = (float*)d_out;

  char* ws = (char*)d_ws;
  unsigned short* xb = (unsigned short*)(ws);                // 8MB
  unsigned short* Wt = (unsigned short*)(ws + (8u << 20));   // 4x2MB (q,k,v,o)
  unsigned short* Qb = (unsigned short*)(ws + (16u << 20));  // 8MB
  unsigned short* Kb = (unsigned short*)(ws + (24u << 20));  // 8MB
  unsigned short* Vp = (unsigned short*)(ws + (32u << 20));  // 8MB
  unsigned short* Ab = (unsigned short*)(ws + (40u << 20));  // 8MB
  unsigned short* Wto = Wt + (size_t)3 * 1024 * 1024;        // ELEMENT offset

  prep<<<dim3(5120), 256, 0, stream>>>(x, Wq, Wk, Wv, Wo, xb, Wt);
  gemm_qkv<<<dim3(768), 256, 0, stream>>>(xb, Wt, Qb, Kb, Vp);
  attn_fm<<<dim3(1024), 256, 0, stream>>>(Qb, Kb, Vp, Ab);
  gemm_out<<<dim3(256), 256, 0, stream>>>(Ab, Wto, out);
}